// Round 16
// baseline (473.505 us; speedup 1.0000x reference)
//
#include <hip/hip_runtime.h>

typedef _Float16 f16;
typedef f16 f16x8 __attribute__((ext_vector_type(8)));
typedef float f32x4 __attribute__((ext_vector_type(4)));

#define EPSBN 1e-3f

// async global->LDS, 16B per lane; lds dest is wave-uniform base (+lane*16 by HW)
__device__ __forceinline__ void stage16(const f16* g, const f16* l) {
    __builtin_amdgcn_global_load_lds(
        (const __attribute__((address_space(1))) unsigned int*)g,
        (__attribute__((address_space(3))) unsigned int*)l,
        16, 0, 0);
}

// Swizzled staging of a [R][32]-f16 K-tile as 16B chunks. LDS slot c holds
// chunk(row=c>>2, kc=(c^(c>>3))&3); chunk(row,kc) sits at slot row*4+(kc^((row>>1)&3)).
__device__ __forceinline__ void stage_swz(const f16* src, int Ksrc, int k0,
                                          const f16* lds, int g, int lane) {
    const int c = g * 64 + lane;
    const int row = c >> 2;
    const int kc = (c ^ (c >> 3)) & 3;
    stage16(src + (size_t)row * Ksrc + k0 + kc * 8, lds + g * 512);
}
// f16 offset of fragment chunk (row, kc=lq); lrh = (lr>>1)&3 (lane-const)
__device__ __forceinline__ int swz_off(int row, int lq, int lrh) {
    return (row * 4 + (lq ^ lrh)) * 8;
}

// ---------------- prep: fold BN into weights, transpose to [N][K] f16, cvt inputs ----------------
__global__ __launch_bounds__(256) void prep_kernel(
    const float* __restrict__ inputs,
    const float* __restrict__ att_w, const float* __restrict__ att_gamma,
    const float* __restrict__ att_beta, const float* __restrict__ att_mean,
    const float* __restrict__ att_var,
    const float* __restrict__ proj_w,
    const float* __restrict__ glu_w, const float* __restrict__ glu_gamma,
    const float* __restrict__ glu_beta, const float* __restrict__ glu_mean,
    const float* __restrict__ glu_var,
    const float* __restrict__ out_w,
    f16* __restrict__ inputs16,
    f16* __restrict__ watt, f16* __restrict__ wproj, f16* __restrict__ wglu,
    f16* __restrict__ wout, float* __restrict__ t_att, float* __restrict__ t_glu)
{
    int tid = blockIdx.x * blockDim.x + threadIdx.x;
    int nth = gridDim.x * blockDim.x;
    for (int i = tid; i < 65536 * 512 / 8; i += nth) {
        float4 u0 = ((const float4*)inputs)[i * 2];
        float4 u1 = ((const float4*)inputs)[i * 2 + 1];
        f16x8 h = {(f16)u0.x, (f16)u0.y, (f16)u0.z, (f16)u0.w,
                   (f16)u1.x, (f16)u1.y, (f16)u1.z, (f16)u1.w};
        ((f16x8*)inputs16)[i] = h;
    }
    for (int i = tid; i < 512 * 512; i += nth) {
        int n = i >> 9, k = i & 511;
        float s = att_gamma[n] * rsqrtf(att_var[n] + EPSBN);
        watt[i] = (f16)(att_w[k * 512 + n] * s);
    }
    for (int i = tid; i < 256 * 512; i += nth) {
        int n = i >> 9, k = i & 511;
        wproj[i] = (f16)(proj_w[k * 256 + n]);
    }
    for (int i = tid; i < 4 * 512 * 256; i += nth) {
        int g = i >> 17, r = i & 131071;
        int n = r >> 8, k = r & 255;
        int c = (n & 1) ? 256 + (n >> 1) : (n >> 1);
        float s = glu_gamma[g * 512 + c] * rsqrtf(glu_var[g * 512 + c] + EPSBN);
        wglu[i] = (f16)(glu_w[g * 131072 + k * 512 + c] * s);
    }
    for (int i = tid; i < 128 * 256; i += nth) {
        int n = i >> 8, k = i & 255;
        wout[i] = (f16)(out_w[k * 128 + n]);
    }
    for (int n = tid; n < 512; n += nth) {
        float s = att_gamma[n] * rsqrtf(att_var[n] + EPSBN);
        t_att[n] = att_beta[n] - att_mean[n] * s;
    }
    for (int i = tid; i < 4 * 512; i += nth) {
        int g = i >> 9, n = i & 511;
        int c = (n & 1) ? 256 + (n >> 1) : (n >> 1);
        float s = glu_gamma[g * 512 + c] * rsqrtf(glu_var[g * 512 + c] + EPSBN);
        t_glu[i] = glu_beta[g * 512 + c] - glu_mean[g * 512 + c] * s;
    }
}

// ---------------- att v6: GEMM + sparsemax + proj, 36.9KB LDS -> 4 blocks/CU ----------------
// 256 threads / 4 waves; block tile 64 rows x 512 cols; wave w: rows w*16..+16, all 512 cols.
// acc[n][j]: row = w*16 + lq*4 + j, col = n*16 + lr.
__global__ __launch_bounds__(256, 2) void att_sparsemax_kernel(
    const f16* __restrict__ in16, const f16* __restrict__ watt,
    const float* __restrict__ t_att, const float* __restrict__ priors,
    const f16* __restrict__ wproj, const float* __restrict__ proj_b,
    float* __restrict__ maskout, float* __restrict__ npout,
    f16* __restrict__ x0out)
{
    __shared__ f16 S[18432];          // 36.9KB: GEMM A=[0,2048) B=[2048,18432); proj Mld=[0,16896)
    f16* Abuf = S;
    f16* Bbuf = S + 2048;
    const int rBase = blockIdx.x * 64;
    const int tid = threadIdx.x;
    const int lane = tid & 63;
    const int w = tid >> 6;
    const int lr = lane & 15, lq = lane >> 4;
    const int lrh = (lr >> 1) & 3;

    f32x4 acc[32];
#pragma unroll
    for (int n = 0; n < 32; n++) acc[n] = (f32x4){0.f, 0.f, 0.f, 0.f};

    const f16* Asrc = in16 + (size_t)rBase * 512;
#pragma unroll 1
    for (int k = 0; k < 16; k++) {
        __syncthreads();   // previous step's readers done
        stage_swz(Asrc, 512, k * 32, Abuf, w, lane);           // 64x32: 256 chunks
#pragma unroll
        for (int i = 0; i < 8; i++)                             // 512x32: 2048 chunks
            stage_swz(watt, 512, k * 32, Bbuf, w * 8 + i, lane);
        __syncthreads();   // staged (compiler drains vmcnt before barrier)
        f16x8 af = *(const f16x8*)&Abuf[swz_off(w * 16 + lr, lq, lrh)];
#pragma unroll
        for (int n = 0; n < 32; n++) {
            f16x8 bf = *(const f16x8*)&Bbuf[swz_off(n * 16 + lr, lq, lrh)];
            acc[n] = __builtin_amdgcn_mfma_f32_16x16x32_f16(af, bf, acc[n], 0, 0, 0);
        }
    }

    // z = (acc + t) * priors
#pragma unroll
    for (int n = 0; n < 32; n++) {
        const float t = t_att[n * 16 + lr];
        const size_t pb = (size_t)(rBase + w * 16 + lq * 4) * 512 + n * 16 + lr;
#pragma unroll
        for (int j = 0; j < 4; j++)
            acc[n][j] = (acc[n][j] + t) * priors[pb + (size_t)j * 512];
    }

    // sparsemax (16-lane groups, 4 rows via j)
    float lo[4], hi[4];
#pragma unroll
    for (int j = 0; j < 4; j++) {
        float m = acc[0][j];
#pragma unroll
        for (int n = 1; n < 32; n++) m = fmaxf(m, acc[n][j]);
#pragma unroll
        for (int d = 1; d < 16; d <<= 1) m = fmaxf(m, __shfl_xor(m, d, 64));
        lo[j] = m - 1.f; hi[j] = m;
    }
    for (int it = 0; it < 10; ++it) {
#pragma unroll
        for (int j = 0; j < 4; j++) {
            const float tau = 0.5f * (lo[j] + hi[j]);
            float s = 0.f;
#pragma unroll
            for (int n = 0; n < 32; n++) s += fmaxf(acc[n][j] - tau, 0.f);
#pragma unroll
            for (int d = 1; d < 16; d <<= 1) s += __shfl_xor(s, d, 64);
            if (s >= 1.f) lo[j] = tau; else hi[j] = tau;
        }
    }
    float tau[4];
#pragma unroll
    for (int j = 0; j < 4; j++) {
        float cnt = 0.f, sm = 0.f;
#pragma unroll
        for (int n = 0; n < 32; n++) {
            if (acc[n][j] > lo[j]) { cnt += 1.f; sm += acc[n][j]; }
        }
#pragma unroll
        for (int d = 1; d < 16; d <<= 1) {
            cnt += __shfl_xor(cnt, d, 64);
            sm += __shfl_xor(sm, d, 64);
        }
        tau[j] = (sm - 1.f) / cnt;
    }

    // mask into acc; write mask, np
#pragma unroll
    for (int n = 0; n < 32; n++) {
        const size_t pb = (size_t)(rBase + w * 16 + lq * 4) * 512 + n * 16 + lr;
#pragma unroll
        for (int j = 0; j < 4; j++) {
            const float mk = fmaxf(acc[n][j] - tau[j], 0.f);
            acc[n][j] = mk;
            maskout[pb + (size_t)j * 512] = mk;
            npout[pb + (size_t)j * 512] = priors[pb + (size_t)j * 512] * (1.f - mk);
        }
    }

    // per half: repack mask -> masked (LDS), proj partial-K with DIRECT-L2 B + prefetch
    f16* Mld = S;   // [64][264]
    f32x4 apr[4][4];
#pragma unroll
    for (int m = 0; m < 4; m++)
#pragma unroll
        for (int n = 0; n < 4; n++) apr[m][n] = (f32x4){0.f, 0.f, 0.f, 0.f};
    const f16* Wpb = wproj + (size_t)(w * 64 + lr) * 512 + lq * 8;  // + n*16*512 + h*256 + kk*32
#pragma unroll
    for (int h = 0; h < 2; h++) {
        __syncthreads();  // h=0: K-loop readers done; h=1: proj h=0 Mld reads done
#pragma unroll
        for (int i = 0; i < 16; i++) {
            const int n = h * 16 + i;       // static index (rule #20)
            const int colh = i * 16 + lr;
#pragma unroll
            for (int j = 0; j < 4; j++)
                Mld[(w * 16 + lq * 4 + j) * 264 + colh] = (f16)acc[n][j];
        }
        __syncthreads();
        // masked = mask * input, in place (per-thread read-then-write)
#pragma unroll
        for (int i = 0; i < 8; i++) {
            const int c = i * 256 + tid;
            const int row = c >> 5, col8 = (c & 31) * 8;
            f16x8 mv = *(const f16x8*)&Mld[row * 264 + col8];
            f16x8 xv = *(const f16x8*)(in16 + (size_t)(rBase + row) * 512 + h * 256 + col8);
            *(f16x8*)&Mld[row * 264 + col8] = mv * xv;
        }
        __syncthreads();  // Mld visible to all waves
        // proj partial-K over this half: 8 steps, no barriers (Mld read-only)
        f16x8 bcur[4];
#pragma unroll
        for (int n = 0; n < 4; n++)
            bcur[n] = *(const f16x8*)(Wpb + (size_t)(n * 16) * 512 + h * 256);
#pragma unroll
        for (int kk = 0; kk < 8; kk++) {
            f16x8 bnxt[4];
            if (kk + 1 < 8) {
#pragma unroll
                for (int n = 0; n < 4; n++)
                    bnxt[n] = *(const f16x8*)(Wpb + (size_t)(n * 16) * 512 + h * 256 + (kk + 1) * 32);
            }
            f16x8 af[4];
#pragma unroll
            for (int m = 0; m < 4; m++)
                af[m] = *(const f16x8*)&Mld[(m * 16 + lr) * 264 + kk * 32 + lq * 8];
#pragma unroll
            for (int m = 0; m < 4; m++)
#pragma unroll
                for (int n = 0; n < 4; n++)
                    apr[m][n] = __builtin_amdgcn_mfma_f32_16x16x32_f16(af[m], bcur[n], apr[m][n], 0, 0, 0);
            if (kk + 1 < 8) {
#pragma unroll
                for (int n = 0; n < 4; n++) bcur[n] = bnxt[n];
            }
        }
    }
    // x0 epilogue: repack apr+b -> Mld, coalesced store
    __syncthreads();
#pragma unroll
    for (int n = 0; n < 4; n++) {
        const int col = w * 64 + n * 16 + lr;
        const float t = proj_b[col];
#pragma unroll
        for (int m = 0; m < 4; m++)
#pragma unroll
            for (int j = 0; j < 4; j++)
                Mld[(m * 16 + lq * 4 + j) * 264 + col] = (f16)(apr[m][n][j] + t);
    }
    __syncthreads();
#pragma unroll
    for (int i = 0; i < 8; i++) {
        const int c = i * 256 + tid;
        const int row = c >> 5, col8 = (c & 31) * 8;
        f16x8 v = *(const f16x8*)&Mld[row * 264 + col8];
        *(f16x8*)(x0out + (size_t)(rBase + row) * 256 + col8) = v;
    }
}

// ---------------- chain v6: 4-wave blocks, 64 rows, X-only LDS (33.8KB -> 4 blocks/CU) ----------------
// 256 threads / 4 waves; wave w: cols [w*128,+128) (GLU), [w*32,+32) (out); direct-L2 B + prefetch.
__global__ __launch_bounds__(256, 2) void chain_kernel(
    const f16* __restrict__ x0g, const f16* __restrict__ wglu,
    const float* __restrict__ t_glu, const f16* __restrict__ wout,
    const float* __restrict__ out_b, float* __restrict__ outp)
{
    __shared__ f16 X[64 * 264];        // 33.8KB, only LDS use
    const int rBase = blockIdx.x * 64;
    const int tid = threadIdx.x;
    const int lane = tid & 63;
    const int w = tid >> 6;        // 0..3
    const int lr = lane & 15, lq = lane >> 4;

    // load X tile from x0: [64][256] = 2048 16B-chunks / 256 thr
#pragma unroll
    for (int i = 0; i < 8; i++) {
        const int c = i * 256 + tid;
        const int row = c >> 5, col8 = (c & 31) * 8;
        f16x8 v = *(const f16x8*)(x0g + (size_t)(rBase + row) * 256 + col8);
        *(f16x8*)&X[row * 264 + col8] = v;
    }
    __syncthreads();

    // ---- 4 GLU blocks: C 64x512 (interleaved val/gate), wave cols [w*128,+128), K=256 ----
#pragma unroll 1
    for (int g = 0; g < 4; ++g) {
        f32x4 acc[4][8];
#pragma unroll
        for (int m = 0; m < 4; m++)
#pragma unroll
            for (int n = 0; n < 8; n++) acc[m][n] = (f32x4){0.f, 0.f, 0.f, 0.f};
        // per-lane B base: row w*128+n*16+lr, col lq*8
        const f16* Wb = wglu + (size_t)g * 131072 + (size_t)(w * 128 + lr) * 256 + lq * 8;
        f16x8 bcur[8];
#pragma unroll
        for (int n = 0; n < 8; n++)
            bcur[n] = *(const f16x8*)(Wb + (size_t)(n * 16) * 256);
#pragma unroll
        for (int k = 0; k < 8; k++) {
            f16x8 bnxt[8];
            if (k + 1 < 8) {
#pragma unroll
                for (int n = 0; n < 8; n++)
                    bnxt[n] = *(const f16x8*)(Wb + (size_t)(n * 16) * 256 + (k + 1) * 32);
            }
            f16x8 af[4];
#pragma unroll
            for (int m = 0; m < 4; m++)
                af[m] = *(const f16x8*)&X[(m * 16 + lr) * 264 + k * 32 + lq * 8];
#pragma unroll
            for (int m = 0; m < 4; m++)
#pragma unroll
                for (int n = 0; n < 8; n++)
                    acc[m][n] = __builtin_amdgcn_mfma_f32_16x16x32_f16(af[m], bcur[n], acc[m][n], 0, 0, 0);
            if (k + 1 < 8) {
#pragma unroll
                for (int n = 0; n < 8; n++) bcur[n] = bnxt[n];
            }
        }
        __syncthreads();  // all waves' X reads done before in-place update
#pragma unroll
        for (int n = 0; n < 8; n++) {
            const int col = w * 128 + n * 16 + lr;
            const float t = t_glu[g * 512 + col];
#pragma unroll
            for (int m = 0; m < 4; m++)
#pragma unroll
                for (int j = 0; j < 4; j++) {
                    float v = acc[m][n][j] + t;
                    float o = __shfl_xor(v, 1, 64);  // val<->gate (adjacent interleaved cols)
                    if (!(lane & 1)) {
                        const int xi = col >> 1;     // in [w*64,+64): owned by this wave
                        const int row = m * 16 + lq * 4 + j;
                        float xn = v * (1.f / (1.f + __expf(-o)));
                        X[row * 264 + xi] = (f16)(xn + (float)X[row * 264 + xi]);
                    }
                }
        }
        __syncthreads();  // X updated before next phase reads
    }

    // ---- out: C 64x128, wave cols [w*32,+32), K=256 ----
    {
        f32x4 acc[4][2];
#pragma unroll
        for (int m = 0; m < 4; m++)
#pragma unroll
            for (int n = 0; n < 2; n++) acc[m][n] = (f32x4){0.f, 0.f, 0.f, 0.f};
        const f16* Wb = wout + (size_t)(w * 32 + lr) * 256 + lq * 8;
        f16x8 bcur[2];
#pragma unroll
        for (int n = 0; n < 2; n++)
            bcur[n] = *(const f16x8*)(Wb + (size_t)(n * 16) * 256);
#pragma unroll
        for (int k = 0; k < 8; k++) {
            f16x8 bnxt[2];
            if (k + 1 < 8) {
#pragma unroll
                for (int n = 0; n < 2; n++)
                    bnxt[n] = *(const f16x8*)(Wb + (size_t)(n * 16) * 256 + (k + 1) * 32);
            }
            f16x8 af[4];
#pragma unroll
            for (int m = 0; m < 4; m++)
                af[m] = *(const f16x8*)&X[(m * 16 + lr) * 264 + k * 32 + lq * 8];
#pragma unroll
            for (int m = 0; m < 4; m++)
#pragma unroll
                for (int n = 0; n < 2; n++)
                    acc[m][n] = __builtin_amdgcn_mfma_f32_16x16x32_f16(af[m], bcur[n], acc[m][n], 0, 0, 0);
            if (k + 1 < 8) {
#pragma unroll
                for (int n = 0; n < 2; n++) bcur[n] = bnxt[n];
            }
        }
#pragma unroll
        for (int n = 0; n < 2; n++) {
            const int col = w * 32 + n * 16 + lr;
            const float t = out_b[col];
#pragma unroll
            for (int m = 0; m < 4; m++)
#pragma unroll
                for (int j = 0; j < 4; j++)
                    outp[(size_t)(rBase + m * 16 + lq * 4 + j) * 128 + col] = acc[m][n][j] + t;
        }
    }
}

extern "C" void kernel_launch(void* const* d_in, const int* in_sizes, int n_in,
                              void* d_out, int out_size, void* d_ws, size_t ws_size,
                              hipStream_t stream)
{
    const float* inputs    = (const float*)d_in[0];
    const float* priors    = (const float*)d_in[1];
    const float* att_w     = (const float*)d_in[2];
    const float* att_gamma = (const float*)d_in[3];
    const float* att_beta  = (const float*)d_in[4];
    const float* att_mean  = (const float*)d_in[5];
    const float* att_var   = (const float*)d_in[6];
    const float* proj_w    = (const float*)d_in[7];
    const float* proj_b    = (const float*)d_in[8];
    const float* glu_w     = (const float*)d_in[9];
    const float* glu_gamma = (const float*)d_in[10];
    const float* glu_beta  = (const float*)d_in[11];
    const float* glu_mean  = (const float*)d_in[12];
    const float* glu_var   = (const float*)d_in[13];
    const float* out_w     = (const float*)d_in[14];
    const float* out_b     = (const float*)d_in[15];

    char* ws = (char*)d_ws;
    f16*   watt     = (f16*)(ws + 0);          // 512*512 f16
    f16*   wproj    = (f16*)(ws + 524288);     // 256*512
    f16*   wglu     = (f16*)(ws + 786432);     // 4*512*256
    f16*   wout     = (f16*)(ws + 1835008);    // 128*256
    float* t_att    = (float*)(ws + 1900544);  // 512
    float* t_glu    = (float*)(ws + 1902592);  // 4*512
    f16*   inputs16 = (f16*)(ws + 2097152);    // 65536*512 f16 (64MB)
    f16*   x0buf    = (f16*)(ws + 69206016);   // 65536*256 f16 (32MB)

    float* outp  = (float*)d_out;
    float* maskp = outp + (size_t)65536 * 128;
    float* npp   = maskp + (size_t)65536 * 512;

    prep_kernel<<<2048, 256, 0, stream>>>(inputs, att_w, att_gamma, att_beta, att_mean,
                                          att_var, proj_w, glu_w, glu_gamma, glu_beta,
                                          glu_mean, glu_var, out_w, inputs16,
                                          watt, wproj, wglu, wout, t_att, t_glu);

    att_sparsemax_kernel<<<1024, 256, 0, stream>>>(
        inputs16, watt, t_att, priors, wproj, proj_b, maskp, npp, x0buf);

    chain_kernel<<<1024, 256, 0, stream>>>(
        x0buf, wglu, t_glu, wout, out_b, outp);
}

// Round 17
// 463.144 us; speedup vs baseline: 1.0224x; 1.0224x over previous
//
#include <hip/hip_runtime.h>

typedef _Float16 f16;
typedef f16 f16x8 __attribute__((ext_vector_type(8)));
typedef float f32x4 __attribute__((ext_vector_type(4)));

#define EPSBN 1e-3f

// async global->LDS, 16B per lane; lds dest is wave-uniform base (+lane*16 by HW)
__device__ __forceinline__ void stage16(const f16* g, const f16* l) {
    __builtin_amdgcn_global_load_lds(
        (const __attribute__((address_space(1))) unsigned int*)g,
        (__attribute__((address_space(3))) unsigned int*)l,
        16, 0, 0);
}

// Swizzled staging of a [R][32]-f16 K-tile as 16B chunks. LDS slot c holds
// chunk(row=c>>2, kc=(c^(c>>3))&3); chunk(row,kc) sits at slot row*4+(kc^((row>>1)&3)).
__device__ __forceinline__ void stage_swz(const f16* src, int Ksrc, int k0,
                                          const f16* lds, int g, int lane) {
    const int c = g * 64 + lane;
    const int row = c >> 2;
    const int kc = (c ^ (c >> 3)) & 3;
    stage16(src + (size_t)row * Ksrc + k0 + kc * 8, lds + g * 512);
}
// f16 offset of fragment chunk (row, kc=lq); lrh = (lr>>1)&3 (lane-const)
__device__ __forceinline__ int swz_off(int row, int lq, int lrh) {
    return (row * 4 + (lq ^ lrh)) * 8;
}

// ---------------- prep: fold BN into weights, transpose to [N][K] f16, cvt inputs ----------------
__global__ __launch_bounds__(256) void prep_kernel(
    const float* __restrict__ inputs,
    const float* __restrict__ att_w, const float* __restrict__ att_gamma,
    const float* __restrict__ att_beta, const float* __restrict__ att_mean,
    const float* __restrict__ att_var,
    const float* __restrict__ proj_w,
    const float* __restrict__ glu_w, const float* __restrict__ glu_gamma,
    const float* __restrict__ glu_beta, const float* __restrict__ glu_mean,
    const float* __restrict__ glu_var,
    const float* __restrict__ out_w,
    f16* __restrict__ inputs16,
    f16* __restrict__ watt, f16* __restrict__ wproj, f16* __restrict__ wglu,
    f16* __restrict__ wout, float* __restrict__ t_att, float* __restrict__ t_glu)
{
    int tid = blockIdx.x * blockDim.x + threadIdx.x;
    int nth = gridDim.x * blockDim.x;
    for (int i = tid; i < 65536 * 512 / 8; i += nth) {
        float4 u0 = ((const float4*)inputs)[i * 2];
        float4 u1 = ((const float4*)inputs)[i * 2 + 1];
        f16x8 h = {(f16)u0.x, (f16)u0.y, (f16)u0.z, (f16)u0.w,
                   (f16)u1.x, (f16)u1.y, (f16)u1.z, (f16)u1.w};
        ((f16x8*)inputs16)[i] = h;
    }
    for (int i = tid; i < 512 * 512; i += nth) {
        int n = i >> 9, k = i & 511;
        float s = att_gamma[n] * rsqrtf(att_var[n] + EPSBN);
        watt[i] = (f16)(att_w[k * 512 + n] * s);
    }
    for (int i = tid; i < 256 * 512; i += nth) {
        int n = i >> 9, k = i & 511;
        wproj[i] = (f16)(proj_w[k * 256 + n]);
    }
    for (int i = tid; i < 4 * 512 * 256; i += nth) {
        int g = i >> 17, r = i & 131071;
        int n = r >> 8, k = r & 255;
        int c = (n & 1) ? 256 + (n >> 1) : (n >> 1);
        float s = glu_gamma[g * 512 + c] * rsqrtf(glu_var[g * 512 + c] + EPSBN);
        wglu[i] = (f16)(glu_w[g * 131072 + k * 512 + c] * s);
    }
    for (int i = tid; i < 128 * 256; i += nth) {
        int n = i >> 8, k = i & 255;
        wout[i] = (f16)(out_w[k * 128 + n]);
    }
    for (int n = tid; n < 512; n += nth) {
        float s = att_gamma[n] * rsqrtf(att_var[n] + EPSBN);
        t_att[n] = att_beta[n] - att_mean[n] * s;
    }
    for (int i = tid; i < 4 * 512; i += nth) {
        int g = i >> 9, n = i & 511;
        int c = (n & 1) ? 256 + (n >> 1) : (n >> 1);
        float s = glu_gamma[g * 512 + c] * rsqrtf(glu_var[g * 512 + c] + EPSBN);
        t_glu[i] = glu_beta[g * 512 + c] - glu_mean[g * 512 + c] * s;
    }
}

// ---------------- att v6: GEMM + sparsemax + proj (round-16, unchanged) ----------------
__global__ __launch_bounds__(256, 2) void att_sparsemax_kernel(
    const f16* __restrict__ in16, const f16* __restrict__ watt,
    const float* __restrict__ t_att, const float* __restrict__ priors,
    const f16* __restrict__ wproj, const float* __restrict__ proj_b,
    float* __restrict__ maskout, float* __restrict__ npout,
    f16* __restrict__ x0out)
{
    __shared__ f16 S[18432];          // 36.9KB: GEMM A=[0,2048) B=[2048,18432); proj Mld=[0,16896)
    f16* Abuf = S;
    f16* Bbuf = S + 2048;
    const int rBase = blockIdx.x * 64;
    const int tid = threadIdx.x;
    const int lane = tid & 63;
    const int w = tid >> 6;
    const int lr = lane & 15, lq = lane >> 4;
    const int lrh = (lr >> 1) & 3;

    f32x4 acc[32];
#pragma unroll
    for (int n = 0; n < 32; n++) acc[n] = (f32x4){0.f, 0.f, 0.f, 0.f};

    const f16* Asrc = in16 + (size_t)rBase * 512;
#pragma unroll 1
    for (int k = 0; k < 16; k++) {
        __syncthreads();   // previous step's readers done
        stage_swz(Asrc, 512, k * 32, Abuf, w, lane);           // 64x32: 256 chunks
#pragma unroll
        for (int i = 0; i < 8; i++)                             // 512x32: 2048 chunks
            stage_swz(watt, 512, k * 32, Bbuf, w * 8 + i, lane);
        __syncthreads();   // staged (compiler drains vmcnt before barrier)
        f16x8 af = *(const f16x8*)&Abuf[swz_off(w * 16 + lr, lq, lrh)];
#pragma unroll
        for (int n = 0; n < 32; n++) {
            f16x8 bf = *(const f16x8*)&Bbuf[swz_off(n * 16 + lr, lq, lrh)];
            acc[n] = __builtin_amdgcn_mfma_f32_16x16x32_f16(af, bf, acc[n], 0, 0, 0);
        }
    }

    // z = (acc + t) * priors
#pragma unroll
    for (int n = 0; n < 32; n++) {
        const float t = t_att[n * 16 + lr];
        const size_t pb = (size_t)(rBase + w * 16 + lq * 4) * 512 + n * 16 + lr;
#pragma unroll
        for (int j = 0; j < 4; j++)
            acc[n][j] = (acc[n][j] + t) * priors[pb + (size_t)j * 512];
    }

    // sparsemax (16-lane groups, 4 rows via j)
    float lo[4], hi[4];
#pragma unroll
    for (int j = 0; j < 4; j++) {
        float m = acc[0][j];
#pragma unroll
        for (int n = 1; n < 32; n++) m = fmaxf(m, acc[n][j]);
#pragma unroll
        for (int d = 1; d < 16; d <<= 1) m = fmaxf(m, __shfl_xor(m, d, 64));
        lo[j] = m - 1.f; hi[j] = m;
    }
    for (int it = 0; it < 10; ++it) {
#pragma unroll
        for (int j = 0; j < 4; j++) {
            const float tau = 0.5f * (lo[j] + hi[j]);
            float s = 0.f;
#pragma unroll
            for (int n = 0; n < 32; n++) s += fmaxf(acc[n][j] - tau, 0.f);
#pragma unroll
            for (int d = 1; d < 16; d <<= 1) s += __shfl_xor(s, d, 64);
            if (s >= 1.f) lo[j] = tau; else hi[j] = tau;
        }
    }
    float tau[4];
#pragma unroll
    for (int j = 0; j < 4; j++) {
        float cnt = 0.f, sm = 0.f;
#pragma unroll
        for (int n = 0; n < 32; n++) {
            if (acc[n][j] > lo[j]) { cnt += 1.f; sm += acc[n][j]; }
        }
#pragma unroll
        for (int d = 1; d < 16; d <<= 1) {
            cnt += __shfl_xor(cnt, d, 64);
            sm += __shfl_xor(sm, d, 64);
        }
        tau[j] = (sm - 1.f) / cnt;
    }

    // mask into acc; write mask, np
#pragma unroll
    for (int n = 0; n < 32; n++) {
        const size_t pb = (size_t)(rBase + w * 16 + lq * 4) * 512 + n * 16 + lr;
#pragma unroll
        for (int j = 0; j < 4; j++) {
            const float mk = fmaxf(acc[n][j] - tau[j], 0.f);
            acc[n][j] = mk;
            maskout[pb + (size_t)j * 512] = mk;
            npout[pb + (size_t)j * 512] = priors[pb + (size_t)j * 512] * (1.f - mk);
        }
    }

    // per half: repack mask -> masked (LDS), proj partial-K with direct-L2 B + prefetch
    f16* Mld = S;   // [64][264]
    f32x4 apr[4][4];
#pragma unroll
    for (int m = 0; m < 4; m++)
#pragma unroll
        for (int n = 0; n < 4; n++) apr[m][n] = (f32x4){0.f, 0.f, 0.f, 0.f};
    const f16* Wpb = wproj + (size_t)(w * 64 + lr) * 512 + lq * 8;
#pragma unroll
    for (int h = 0; h < 2; h++) {
        __syncthreads();
#pragma unroll
        for (int i = 0; i < 16; i++) {
            const int n = h * 16 + i;       // static index (rule #20)
            const int colh = i * 16 + lr;
#pragma unroll
            for (int j = 0; j < 4; j++)
                Mld[(w * 16 + lq * 4 + j) * 264 + colh] = (f16)acc[n][j];
        }
        __syncthreads();
#pragma unroll
        for (int i = 0; i < 8; i++) {
            const int c = i * 256 + tid;
            const int row = c >> 5, col8 = (c & 31) * 8;
            f16x8 mv = *(const f16x8*)&Mld[row * 264 + col8];
            f16x8 xv = *(const f16x8*)(in16 + (size_t)(rBase + row) * 512 + h * 256 + col8);
            *(f16x8*)&Mld[row * 264 + col8] = mv * xv;
        }
        __syncthreads();
        f16x8 bcur[4];
#pragma unroll
        for (int n = 0; n < 4; n++)
            bcur[n] = *(const f16x8*)(Wpb + (size_t)(n * 16) * 512 + h * 256);
#pragma unroll
        for (int kk = 0; kk < 8; kk++) {
            f16x8 bnxt[4];
            if (kk + 1 < 8) {
#pragma unroll
                for (int n = 0; n < 4; n++)
                    bnxt[n] = *(const f16x8*)(Wpb + (size_t)(n * 16) * 512 + h * 256 + (kk + 1) * 32);
            }
            f16x8 af[4];
#pragma unroll
            for (int m = 0; m < 4; m++)
                af[m] = *(const f16x8*)&Mld[(m * 16 + lr) * 264 + kk * 32 + lq * 8];
#pragma unroll
            for (int m = 0; m < 4; m++)
#pragma unroll
                for (int n = 0; n < 4; n++)
                    apr[m][n] = __builtin_amdgcn_mfma_f32_16x16x32_f16(af[m], bcur[n], apr[m][n], 0, 0, 0);
            if (kk + 1 < 8) {
#pragma unroll
                for (int n = 0; n < 4; n++) bcur[n] = bnxt[n];
            }
        }
    }
    __syncthreads();
#pragma unroll
    for (int n = 0; n < 4; n++) {
        const int col = w * 64 + n * 16 + lr;
        const float t = proj_b[col];
#pragma unroll
        for (int m = 0; m < 4; m++)
#pragma unroll
            for (int j = 0; j < 4; j++)
                Mld[(m * 16 + lq * 4 + j) * 264 + col] = (f16)(apr[m][n][j] + t);
    }
    __syncthreads();
#pragma unroll
    for (int i = 0; i < 8; i++) {
        const int c = i * 256 + tid;
        const int row = c >> 5, col8 = (c & 31) * 8;
        f16x8 v = *(const f16x8*)&Mld[row * 264 + col8];
        *(f16x8*)(x0out + (size_t)(rBase + row) * 256 + col8) = v;
    }
}

// ---------------- chain v8: 1024 threads / 16 waves, wave 64x32, <=128 unified regs ----------------
// Block = 64 rows x 512 cols; wave w: cols [w*32,+32) (GLU). acc[4][2] = 32 AGPR.
// X[64][264] only LDS; direct-L2 B frags, 1-step prefetch; no in-loop barriers.
__global__ __launch_bounds__(1024, 4) void chain_kernel(
    const f16* __restrict__ x0g, const f16* __restrict__ wglu,
    const float* __restrict__ t_glu, const f16* __restrict__ wout,
    const float* __restrict__ out_b, float* __restrict__ outp)
{
    __shared__ f16 X[64 * 264];        // 33.8KB
    const int rBase = blockIdx.x * 64;
    const int tid = threadIdx.x;
    const int lane = tid & 63;
    const int w = tid >> 6;        // 0..15
    const int lr = lane & 15, lq = lane >> 4;

    // load X tile from x0: [64][256] = 2048 16B-chunks / 1024 thr
#pragma unroll
    for (int i = 0; i < 2; i++) {
        const int c = i * 1024 + tid;
        const int row = c >> 5, col8 = (c & 31) * 8;
        f16x8 v = *(const f16x8*)(x0g + (size_t)(rBase + row) * 256 + col8);
        *(f16x8*)&X[row * 264 + col8] = v;
    }
    __syncthreads();

    // ---- 4 GLU blocks: C 64x512 (interleaved val/gate), wave cols [w*32,+32), K=256 ----
#pragma unroll 1
    for (int g = 0; g < 4; ++g) {
        f32x4 acc[4][2];
#pragma unroll
        for (int m = 0; m < 4; m++)
#pragma unroll
            for (int n = 0; n < 2; n++) acc[m][n] = (f32x4){0.f, 0.f, 0.f, 0.f};
        const f16* Wb = wglu + (size_t)g * 131072 + (size_t)(w * 32 + lr) * 256 + lq * 8;
        f16x8 bcur[2];
#pragma unroll
        for (int n = 0; n < 2; n++)
            bcur[n] = *(const f16x8*)(Wb + (size_t)(n * 16) * 256);
#pragma unroll
        for (int k = 0; k < 8; k++) {
            f16x8 bnxt[2];
            if (k + 1 < 8) {
#pragma unroll
                for (int n = 0; n < 2; n++)
                    bnxt[n] = *(const f16x8*)(Wb + (size_t)(n * 16) * 256 + (k + 1) * 32);
            }
            f16x8 af[4];
#pragma unroll
            for (int m = 0; m < 4; m++)
                af[m] = *(const f16x8*)&X[(m * 16 + lr) * 264 + k * 32 + lq * 8];
#pragma unroll
            for (int m = 0; m < 4; m++)
#pragma unroll
                for (int n = 0; n < 2; n++)
                    acc[m][n] = __builtin_amdgcn_mfma_f32_16x16x32_f16(af[m], bcur[n], acc[m][n], 0, 0, 0);
            if (k + 1 < 8) {
#pragma unroll
                for (int n = 0; n < 2; n++) bcur[n] = bnxt[n];
            }
        }
        __syncthreads();  // all waves' X reads done before in-place update
#pragma unroll
        for (int n = 0; n < 2; n++) {
            const int col = w * 32 + n * 16 + lr;
            const float t = t_glu[g * 512 + col];
#pragma unroll
            for (int m = 0; m < 4; m++)
#pragma unroll
                for (int j = 0; j < 4; j++) {
                    float v = acc[m][n][j] + t;
                    float o = __shfl_xor(v, 1, 64);  // val<->gate (adjacent interleaved cols)
                    if (!(lane & 1)) {
                        const int xi = col >> 1;     // in [w*16,+16): owned by this wave
                        const int row = m * 16 + lq * 4 + j;
                        float xn = v * (1.f / (1.f + __expf(-o)));
                        X[row * 264 + xi] = (f16)(xn + (float)X[row * 264 + xi]);
                    }
                }
        }
        __syncthreads();  // X updated before next phase reads
    }

    // ---- out: C 64x128; wave tile 32 rows x 16 cols: wr = w&1, wc = w>>1 ----
    {
        const int wr = w & 1, wc = w >> 1;   // wc 0..7
        f32x4 acc[2];
#pragma unroll
        for (int m = 0; m < 2; m++) acc[m] = (f32x4){0.f, 0.f, 0.f, 0.f};
        const f16* Wb = wout + (size_t)(wc * 16 + lr) * 256 + lq * 8;
        f16x8 bcur = *(const f16x8*)(Wb);
#pragma unroll
        for (int k = 0; k < 8; k++) {
            f16x8 bnxt;
            if (k + 1 < 8) bnxt = *(const f16x8*)(Wb + (k + 1) * 32);
            f16x8 af[2];
#pragma unroll
            for (int m = 0; m < 2; m++)
                af[m] = *(const f16x8*)&X[(wr * 32 + m * 16 + lr) * 264 + k * 32 + lq * 8];
#pragma unroll
            for (int m = 0; m < 2; m++)
                acc[m] = __builtin_amdgcn_mfma_f32_16x16x32_f16(af[m], bcur, acc[m], 0, 0, 0);
            if (k + 1 < 8) bcur = bnxt;
        }
        const int col = wc * 16 + lr;
        const float t = out_b[col];
#pragma unroll
        for (int m = 0; m < 2; m++)
#pragma unroll
            for (int j = 0; j < 4; j++)
                outp[(size_t)(rBase + wr * 32 + m * 16 + lq * 4 + j) * 128 + col] = acc[m][j] + t;
    }
}

extern "C" void kernel_launch(void* const* d_in, const int* in_sizes, int n_in,
                              void* d_out, int out_size, void* d_ws, size_t ws_size,
                              hipStream_t stream)
{
    const float* inputs    = (const float*)d_in[0];
    const float* priors    = (const float*)d_in[1];
    const float* att_w     = (const float*)d_in[2];
    const float* att_gamma = (const float*)d_in[3];
    const float* att_beta  = (const float*)d_in[4];
    const float* att_mean  = (const float*)d_in[5];
    const float* att_var   = (const float*)d_in[6];
    const float* proj_w    = (const float*)d_in[7];
    const float* proj_b    = (const float*)d_in[8];
    const float* glu_w     = (const float*)d_in[9];
    const float* glu_gamma = (const float*)d_in[10];
    const float* glu_beta  = (const float*)d_in[11];
    const float* glu_mean  = (const float*)d_in[12];
    const float* glu_var   = (const float*)d_in[13];
    const float* out_w     = (const float*)d_in[14];
    const float* out_b     = (const float*)d_in[15];

    char* ws = (char*)d_ws;
    f16*   watt     = (f16*)(ws + 0);          // 512*512 f16
    f16*   wproj    = (f16*)(ws + 524288);     // 256*512
    f16*   wglu     = (f16*)(ws + 786432);     // 4*512*256
    f16*   wout     = (f16*)(ws + 1835008);    // 128*256
    float* t_att    = (float*)(ws + 1900544);  // 512
    float* t_glu    = (float*)(ws + 1902592);  // 4*512
    f16*   inputs16 = (f16*)(ws + 2097152);    // 65536*512 f16 (64MB)
    f16*   x0buf    = (f16*)(ws + 69206016);   // 65536*256 f16 (32MB)

    float* outp  = (float*)d_out;
    float* maskp = outp + (size_t)65536 * 128;
    float* npp   = maskp + (size_t)65536 * 512;

    prep_kernel<<<2048, 256, 0, stream>>>(inputs, att_w, att_gamma, att_beta, att_mean,
                                          att_var, proj_w, glu_w, glu_gamma, glu_beta,
                                          glu_mean, glu_var, out_w, inputs16,
                                          watt, wproj, wglu, wout, t_att, t_glu);

    att_sparsemax_kernel<<<1024, 256, 0, stream>>>(
        inputs16, watt, t_att, priors, wproj, proj_b, maskp, npp, x0buf);

    chain_kernel<<<1024, 1024, 0, stream>>>(
        x0buf, wglu, t_glu, wout, out_b, outp);
}

// Round 18
// 440.061 us; speedup vs baseline: 1.0760x; 1.0525x over previous
//
#include <hip/hip_runtime.h>

typedef _Float16 f16;
typedef f16 f16x8 __attribute__((ext_vector_type(8)));
typedef float f32x4 __attribute__((ext_vector_type(4)));

#define EPSBN 1e-3f

// async global->LDS, 16B per lane; lds dest is wave-uniform base (+lane*16 by HW)
__device__ __forceinline__ void stage16(const f16* g, const f16* l) {
    __builtin_amdgcn_global_load_lds(
        (const __attribute__((address_space(1))) unsigned int*)g,
        (__attribute__((address_space(3))) unsigned int*)l,
        16, 0, 0);
}

// Swizzled staging of a [R][32]-f16 K-tile as 16B chunks. LDS slot c holds
// chunk(row=c>>2, kc=(c^(c>>3))&3); chunk(row,kc) sits at slot row*4+(kc^((row>>1)&3)).
__device__ __forceinline__ void stage_swz(const f16* src, int Ksrc, int k0,
                                          const f16* lds, int g, int lane) {
    const int c = g * 64 + lane;
    const int row = c >> 2;
    const int kc = (c ^ (c >> 3)) & 3;
    stage16(src + (size_t)row * Ksrc + k0 + kc * 8, lds + g * 512);
}
// f16 offset of fragment chunk (row, kc=lq); lrh = (lr>>1)&3 (lane-const)
__device__ __forceinline__ int swz_off(int row, int lq, int lrh) {
    return (row * 4 + (lq ^ lrh)) * 8;
}

// ---------------- prep: fold BN into weights, transpose to [N][K] f16, cvt inputs ----------------
__global__ __launch_bounds__(256) void prep_kernel(
    const float* __restrict__ inputs,
    const float* __restrict__ att_w, const float* __restrict__ att_gamma,
    const float* __restrict__ att_beta, const float* __restrict__ att_mean,
    const float* __restrict__ att_var,
    const float* __restrict__ proj_w,
    const float* __restrict__ glu_w, const float* __restrict__ glu_gamma,
    const float* __restrict__ glu_beta, const float* __restrict__ glu_mean,
    const float* __restrict__ glu_var,
    const float* __restrict__ out_w,
    f16* __restrict__ inputs16,
    f16* __restrict__ watt, f16* __restrict__ wproj, f16* __restrict__ wglu,
    f16* __restrict__ wout, float* __restrict__ t_att, float* __restrict__ t_glu)
{
    int tid = blockIdx.x * blockDim.x + threadIdx.x;
    int nth = gridDim.x * blockDim.x;
    for (int i = tid; i < 65536 * 512 / 8; i += nth) {
        float4 u0 = ((const float4*)inputs)[i * 2];
        float4 u1 = ((const float4*)inputs)[i * 2 + 1];
        f16x8 h = {(f16)u0.x, (f16)u0.y, (f16)u0.z, (f16)u0.w,
                   (f16)u1.x, (f16)u1.y, (f16)u1.z, (f16)u1.w};
        ((f16x8*)inputs16)[i] = h;
    }
    for (int i = tid; i < 512 * 512; i += nth) {
        int n = i >> 9, k = i & 511;
        float s = att_gamma[n] * rsqrtf(att_var[n] + EPSBN);
        watt[i] = (f16)(att_w[k * 512 + n] * s);
    }
    for (int i = tid; i < 256 * 512; i += nth) {
        int n = i >> 9, k = i & 511;
        wproj[i] = (f16)(proj_w[k * 256 + n]);
    }
    for (int i = tid; i < 4 * 512 * 256; i += nth) {
        int g = i >> 17, r = i & 131071;
        int n = r >> 8, k = r & 255;
        int c = (n & 1) ? 256 + (n >> 1) : (n >> 1);
        float s = glu_gamma[g * 512 + c] * rsqrtf(glu_var[g * 512 + c] + EPSBN);
        wglu[i] = (f16)(glu_w[g * 131072 + k * 512 + c] * s);
    }
    for (int i = tid; i < 128 * 256; i += nth) {
        int n = i >> 8, k = i & 255;
        wout[i] = (f16)(out_w[k * 128 + n]);
    }
    for (int n = tid; n < 512; n += nth) {
        float s = att_gamma[n] * rsqrtf(att_var[n] + EPSBN);
        t_att[n] = att_beta[n] - att_mean[n] * s;
    }
    for (int i = tid; i < 4 * 512; i += nth) {
        int g = i >> 9, n = i & 511;
        int c = (n & 1) ? 256 + (n >> 1) : (n >> 1);
        float s = glu_gamma[g * 512 + c] * rsqrtf(glu_var[g * 512 + c] + EPSBN);
        t_glu[i] = glu_beta[g * 512 + c] - glu_mean[g * 512 + c] * s;
    }
}

// ---------------- mega-fused: att GEMM + sparsemax + proj + 4xGLU + out ----------------
// 256 threads / 4 waves; block = 64 rows. X never leaves LDS after proj.
// att acc[n][j]: row = w*16 + lq*4 + j, col = n*16 + lr.
__global__ __launch_bounds__(256, 2) void fused_kernel(
    const f16* __restrict__ in16, const f16* __restrict__ watt,
    const float* __restrict__ t_att, const float* __restrict__ priors,
    const f16* __restrict__ wproj, const float* __restrict__ proj_b,
    const f16* __restrict__ wglu, const float* __restrict__ t_glu,
    const f16* __restrict__ wout, const float* __restrict__ out_b,
    float* __restrict__ maskout, float* __restrict__ npout,
    float* __restrict__ outp)
{
    __shared__ f16 S[18432];          // GEMM: A=[0,2048) B=[2048,18432); then X/Mld=[0,16896)
    f16* Abuf = S;
    f16* Bbuf = S + 2048;
    const int rBase = blockIdx.x * 64;
    const int tid = threadIdx.x;
    const int lane = tid & 63;
    const int w = tid >> 6;
    const int lr = lane & 15, lq = lane >> 4;
    const int lrh = (lr >> 1) & 3;

    f32x4 acc[32];
#pragma unroll
    for (int n = 0; n < 32; n++) acc[n] = (f32x4){0.f, 0.f, 0.f, 0.f};

    const f16* Asrc = in16 + (size_t)rBase * 512;
#pragma unroll 1
    for (int k = 0; k < 16; k++) {
        __syncthreads();
        stage_swz(Asrc, 512, k * 32, Abuf, w, lane);           // 64x32: 256 chunks
#pragma unroll
        for (int i = 0; i < 8; i++)                             // 512x32: 2048 chunks
            stage_swz(watt, 512, k * 32, Bbuf, w * 8 + i, lane);
        __syncthreads();
        f16x8 af = *(const f16x8*)&Abuf[swz_off(w * 16 + lr, lq, lrh)];
#pragma unroll
        for (int n = 0; n < 32; n++) {
            f16x8 bf = *(const f16x8*)&Bbuf[swz_off(n * 16 + lr, lq, lrh)];
            acc[n] = __builtin_amdgcn_mfma_f32_16x16x32_f16(af, bf, acc[n], 0, 0, 0);
        }
    }

    // z = (acc + t) * priors
#pragma unroll
    for (int n = 0; n < 32; n++) {
        const float t = t_att[n * 16 + lr];
        const size_t pb = (size_t)(rBase + w * 16 + lq * 4) * 512 + n * 16 + lr;
#pragma unroll
        for (int j = 0; j < 4; j++)
            acc[n][j] = (acc[n][j] + t) * priors[pb + (size_t)j * 512];
    }

    // sparsemax (16-lane groups, 4 rows via j)
    float lo[4], hi[4];
#pragma unroll
    for (int j = 0; j < 4; j++) {
        float m = acc[0][j];
#pragma unroll
        for (int n = 1; n < 32; n++) m = fmaxf(m, acc[n][j]);
#pragma unroll
        for (int d = 1; d < 16; d <<= 1) m = fmaxf(m, __shfl_xor(m, d, 64));
        lo[j] = m - 1.f; hi[j] = m;
    }
    for (int it = 0; it < 10; ++it) {
#pragma unroll
        for (int j = 0; j < 4; j++) {
            const float tau = 0.5f * (lo[j] + hi[j]);
            float s = 0.f;
#pragma unroll
            for (int n = 0; n < 32; n++) s += fmaxf(acc[n][j] - tau, 0.f);
#pragma unroll
            for (int d = 1; d < 16; d <<= 1) s += __shfl_xor(s, d, 64);
            if (s >= 1.f) lo[j] = tau; else hi[j] = tau;
        }
    }
    float tau[4];
#pragma unroll
    for (int j = 0; j < 4; j++) {
        float cnt = 0.f, sm = 0.f;
#pragma unroll
        for (int n = 0; n < 32; n++) {
            if (acc[n][j] > lo[j]) { cnt += 1.f; sm += acc[n][j]; }
        }
#pragma unroll
        for (int d = 1; d < 16; d <<= 1) {
            cnt += __shfl_xor(cnt, d, 64);
            sm += __shfl_xor(sm, d, 64);
        }
        tau[j] = (sm - 1.f) / cnt;
    }

    // mask into acc; write mask, np
#pragma unroll
    for (int n = 0; n < 32; n++) {
        const size_t pb = (size_t)(rBase + w * 16 + lq * 4) * 512 + n * 16 + lr;
#pragma unroll
        for (int j = 0; j < 4; j++) {
            const float mk = fmaxf(acc[n][j] - tau[j], 0.f);
            acc[n][j] = mk;
            maskout[pb + (size_t)j * 512] = mk;
            npout[pb + (size_t)j * 512] = priors[pb + (size_t)j * 512] * (1.f - mk);
        }
    }

    // proj per 256-col half: repack mask -> masked (LDS), partial-K with direct-L2 B + prefetch
    f16* Mld = S;   // [64][264]
    f32x4 apr[4][4];
#pragma unroll
    for (int m = 0; m < 4; m++)
#pragma unroll
        for (int n = 0; n < 4; n++) apr[m][n] = (f32x4){0.f, 0.f, 0.f, 0.f};
    const f16* Wpb = wproj + (size_t)(w * 64 + lr) * 512 + lq * 8;
#pragma unroll
    for (int h = 0; h < 2; h++) {
        __syncthreads();
#pragma unroll
        for (int i = 0; i < 16; i++) {
            const int n = h * 16 + i;       // static index (rule #20)
            const int colh = i * 16 + lr;
#pragma unroll
            for (int j = 0; j < 4; j++)
                Mld[(w * 16 + lq * 4 + j) * 264 + colh] = (f16)acc[n][j];
        }
        __syncthreads();
#pragma unroll
        for (int i = 0; i < 8; i++) {
            const int c = i * 256 + tid;
            const int row = c >> 5, col8 = (c & 31) * 8;
            f16x8 mv = *(const f16x8*)&Mld[row * 264 + col8];
            f16x8 xv = *(const f16x8*)(in16 + (size_t)(rBase + row) * 512 + h * 256 + col8);
            *(f16x8*)&Mld[row * 264 + col8] = mv * xv;
        }
        __syncthreads();
        f16x8 bcur[4];
#pragma unroll
        for (int n = 0; n < 4; n++)
            bcur[n] = *(const f16x8*)(Wpb + (size_t)(n * 16) * 512 + h * 256);
#pragma unroll
        for (int kk = 0; kk < 8; kk++) {
            f16x8 bnxt[4];
            if (kk + 1 < 8) {
#pragma unroll
                for (int n = 0; n < 4; n++)
                    bnxt[n] = *(const f16x8*)(Wpb + (size_t)(n * 16) * 512 + h * 256 + (kk + 1) * 32);
            }
            f16x8 af[4];
#pragma unroll
            for (int m = 0; m < 4; m++)
                af[m] = *(const f16x8*)&Mld[(m * 16 + lr) * 264 + kk * 32 + lq * 8];
#pragma unroll
            for (int m = 0; m < 4; m++)
#pragma unroll
                for (int n = 0; n < 4; n++)
                    apr[m][n] = __builtin_amdgcn_mfma_f32_16x16x32_f16(af[m], bcur[n], apr[m][n], 0, 0, 0);
            if (kk + 1 < 8) {
#pragma unroll
                for (int n = 0; n < 4; n++) bcur[n] = bnxt[n];
            }
        }
    }
    // X = proj result (stays in LDS; X aliases Mld/S with [64][264] layout)
    __syncthreads();
#pragma unroll
    for (int n = 0; n < 4; n++) {
        const int col = w * 64 + n * 16 + lr;
        const float t = proj_b[col];
#pragma unroll
        for (int m = 0; m < 4; m++)
#pragma unroll
            for (int j = 0; j < 4; j++)
                Mld[(m * 16 + lq * 4 + j) * 264 + col] = (f16)(apr[m][n][j] + t);
    }
    __syncthreads();

    // ---- 4 GLU blocks: C 64x512 (interleaved val/gate), wave cols [w*128,+128), K=256 ----
    f16* X = S;  // [64][264]
#pragma unroll 1
    for (int g = 0; g < 4; ++g) {
        f32x4 gacc[4][8];
#pragma unroll
        for (int m = 0; m < 4; m++)
#pragma unroll
            for (int n = 0; n < 8; n++) gacc[m][n] = (f32x4){0.f, 0.f, 0.f, 0.f};
        const f16* Wb = wglu + (size_t)g * 131072 + (size_t)(w * 128 + lr) * 256 + lq * 8;
        f16x8 bcur[8];
#pragma unroll
        for (int n = 0; n < 8; n++)
            bcur[n] = *(const f16x8*)(Wb + (size_t)(n * 16) * 256);
#pragma unroll
        for (int k = 0; k < 8; k++) {
            f16x8 bnxt[8];
            if (k + 1 < 8) {
#pragma unroll
                for (int n = 0; n < 8; n++)
                    bnxt[n] = *(const f16x8*)(Wb + (size_t)(n * 16) * 256 + (k + 1) * 32);
            }
            f16x8 af[4];
#pragma unroll
            for (int m = 0; m < 4; m++)
                af[m] = *(const f16x8*)&X[(m * 16 + lr) * 264 + k * 32 + lq * 8];
#pragma unroll
            for (int m = 0; m < 4; m++)
#pragma unroll
                for (int n = 0; n < 8; n++)
                    gacc[m][n] = __builtin_amdgcn_mfma_f32_16x16x32_f16(af[m], bcur[n], gacc[m][n], 0, 0, 0);
            if (k + 1 < 8) {
#pragma unroll
                for (int n = 0; n < 8; n++) bcur[n] = bnxt[n];
            }
        }
        __syncthreads();  // all waves' X reads done before in-place update
#pragma unroll
        for (int n = 0; n < 8; n++) {
            const int col = w * 128 + n * 16 + lr;
            const float t = t_glu[g * 512 + col];
#pragma unroll
            for (int m = 0; m < 4; m++)
#pragma unroll
                for (int j = 0; j < 4; j++) {
                    float v = gacc[m][n][j] + t;
                    float o = __shfl_xor(v, 1, 64);  // val<->gate (adjacent interleaved cols)
                    if (!(lane & 1)) {
                        const int xi = col >> 1;     // in [w*64,+64): owned by this wave
                        const int row = m * 16 + lq * 4 + j;
                        float xn = v * (1.f / (1.f + __expf(-o)));
                        X[row * 264 + xi] = (f16)(xn + (float)X[row * 264 + xi]);
                    }
                }
        }
        __syncthreads();  // X updated before next phase reads
    }

    // ---- out: C 64x128, wave cols [w*32,+32), K=256 ----
    {
        f32x4 oacc[4][2];
#pragma unroll
        for (int m = 0; m < 4; m++)
#pragma unroll
            for (int n = 0; n < 2; n++) oacc[m][n] = (f32x4){0.f, 0.f, 0.f, 0.f};
        const f16* Wb = wout + (size_t)(w * 32 + lr) * 256 + lq * 8;
        f16x8 bcur[2];
#pragma unroll
        for (int n = 0; n < 2; n++)
            bcur[n] = *(const f16x8*)(Wb + (size_t)(n * 16) * 256);
#pragma unroll
        for (int k = 0; k < 8; k++) {
            f16x8 bnxt[2];
            if (k + 1 < 8) {
#pragma unroll
                for (int n = 0; n < 2; n++)
                    bnxt[n] = *(const f16x8*)(Wb + (size_t)(n * 16) * 256 + (k + 1) * 32);
            }
            f16x8 af[4];
#pragma unroll
            for (int m = 0; m < 4; m++)
                af[m] = *(const f16x8*)&X[(m * 16 + lr) * 264 + k * 32 + lq * 8];
#pragma unroll
            for (int m = 0; m < 4; m++)
#pragma unroll
                for (int n = 0; n < 2; n++)
                    oacc[m][n] = __builtin_amdgcn_mfma_f32_16x16x32_f16(af[m], bcur[n], oacc[m][n], 0, 0, 0);
            if (k + 1 < 8) {
#pragma unroll
                for (int n = 0; n < 2; n++) bcur[n] = bnxt[n];
            }
        }
#pragma unroll
        for (int n = 0; n < 2; n++) {
            const int col = w * 32 + n * 16 + lr;
            const float t = out_b[col];
#pragma unroll
            for (int m = 0; m < 4; m++)
#pragma unroll
                for (int j = 0; j < 4; j++)
                    outp[(size_t)(rBase + m * 16 + lq * 4 + j) * 128 + col] = oacc[m][n][j] + t;
        }
    }
}

extern "C" void kernel_launch(void* const* d_in, const int* in_sizes, int n_in,
                              void* d_out, int out_size, void* d_ws, size_t ws_size,
                              hipStream_t stream)
{
    const float* inputs    = (const float*)d_in[0];
    const float* priors    = (const float*)d_in[1];
    const float* att_w     = (const float*)d_in[2];
    const float* att_gamma = (const float*)d_in[3];
    const float* att_beta  = (const float*)d_in[4];
    const float* att_mean  = (const float*)d_in[5];
    const float* att_var   = (const float*)d_in[6];
    const float* proj_w    = (const float*)d_in[7];
    const float* proj_b    = (const float*)d_in[8];
    const float* glu_w     = (const float*)d_in[9];
    const float* glu_gamma = (const float*)d_in[10];
    const float* glu_beta  = (const float*)d_in[11];
    const float* glu_mean  = (const float*)d_in[12];
    const float* glu_var   = (const float*)d_in[13];
    const float* out_w     = (const float*)d_in[14];
    const float* out_b     = (const float*)d_in[15];

    char* ws = (char*)d_ws;
    f16*   watt     = (f16*)(ws + 0);          // 512*512 f16
    f16*   wproj    = (f16*)(ws + 524288);     // 256*512
    f16*   wglu     = (f16*)(ws + 786432);     // 4*512*256
    f16*   wout     = (f16*)(ws + 1835008);    // 128*256
    float* t_att    = (float*)(ws + 1900544);  // 512
    float* t_glu    = (float*)(ws + 1902592);  // 4*512
    f16*   inputs16 = (f16*)(ws + 2097152);    // 65536*512 f16 (64MB)

    float* outp  = (float*)d_out;
    float* maskp = outp + (size_t)65536 * 128;
    float* npp   = maskp + (size_t)65536 * 512;

    prep_kernel<<<2048, 256, 0, stream>>>(inputs, att_w, att_gamma, att_beta, att_mean,
                                          att_var, proj_w, glu_w, glu_gamma, glu_beta,
                                          glu_mean, glu_var, out_w, inputs16,
                                          watt, wproj, wglu, wout, t_att, t_glu);

    fused_kernel<<<1024, 256, 0, stream>>>(
        inputs16, watt, t_att, priors, wproj, proj_b, wglu, t_glu, wout, out_b,
        maskp, npp, outp);
}